// Round 2
// baseline (732.601 us; speedup 1.0000x reference)
//
#include <hip/hip_runtime.h>
#include <hip/hip_fp16.h>

// GraphNN_KNN: N=50000 nodes, E=800000 edges, H=64.
// msg = relu([x_i, x_j-x_i, ef] @ W + b) == relu(u[dst] + v[src] + ef*we)
// with u = x@(Wt-Wm)+b, v = x@Wm. u/v GEMMs use MFMA 16x16x32_f16 with
// split-fp16 inputs (3 product terms) for fp32-level accuracy; outputs fp16.
// This round: (a) em_edge/ec_edge gather loops unrolled 4-wide (edge passes
// are latency-bound: ~20% of BW roofline; 4 loads in flight halves serial
// chain); (b) uv GEMM reads W fragments straight from global (coalesced,
// L2-hot) -> no W staging, no barrier, LDS 9KB.

#define NN 50000
#define NE 800000
#define PER 200000      // E / 4 orders
#define HD 64
#define NKEY 250112     // 4*NN em keys + NN ec keys, padded to 977*256
#define GB_CNT 3125     // NE/256
#define GB_PREP 192     // 12*4096/256
#define GB_LIN 782      // ceil(NN/64)
#define GB_KEYS 977     // NKEY/256

typedef _Float16 half8 __attribute__((ext_vector_type(8)));
typedef float float4v __attribute__((ext_vector_type(4)));

struct UvLds {
    _Float16 rp[4 * 16 * 72];   // per-wave output repack only
};

// ---------------- front mega-kernel: count | prep_w | lin0 -----------------
__global__ __launch_bounds__(256) void k_front(
        const int* __restrict__ ei, int* __restrict__ cnt,
        uchar2* __restrict__ rank,
        const float* __restrict__ em_w, const float* __restrict__ ec_w,
        _Float16* __restrict__ wh,
        const float* __restrict__ xin, const float* __restrict__ W0,
        const float* __restrict__ b0, float* __restrict__ x) {
    __shared__ float xs[64][11];
    int t = threadIdx.x;
    if (blockIdx.x < GB_CNT) {
        // ---- count (atomic histogram + rank capture) ----
        int e = blockIdx.x * 256 + t;           // grid exact: e < NE
        int src = ei[e];
        int dst = ei[NE + e];
        int o = e / PER;
        int r1 = atomicAdd(&cnt[o * NN + src], 1);
        int r2 = atomicAdd(&cnt[4 * NN + dst], 1);
        rank[e] = make_uchar2((unsigned char)r1, (unsigned char)r2);
    } else if (blockIdx.x < GB_CNT + GB_PREP) {
        // ---- weight prep: split-fp16, transposed [n][k] ----
        // mats 0-2 emWu, 3-5 emWv, 6-8 ecWu, 9-11 ecWv; lo parts at +12.
        int idx = (blockIdx.x - GB_CNT) * 256 + t;   // < 12*4096
        int mat = idx >> 12, pos = idx & 4095;
        int n = pos >> 6, k = pos & 63;
        float val;
        if (mat < 3)      { const float* B = em_w + mat * 129 * 64;     val = B[k*64+n] - B[(64+k)*64+n]; }
        else if (mat < 6) { const float* B = em_w + (mat-3) * 129 * 64; val = B[(64+k)*64+n]; }
        else if (mat < 9) { const float* B = ec_w + (mat-6) * 128 * 64; val = B[k*64+n] - B[(64+k)*64+n]; }
        else              { const float* B = ec_w + (mat-9) * 128 * 64; val = B[(64+k)*64+n]; }
        _Float16 h = (_Float16)val;
        _Float16 l = (_Float16)(val - (float)h);
        wh[(size_t)mat * 4096 + n * 64 + k] = h;
        wh[(size_t)(12 + mat) * 4096 + n * 64 + k] = l;
    } else {
        // ---- lin0: x = relu(xin @ W0 + b0), K=10 ----
        const int K = 10;
        int n0 = (blockIdx.x - GB_CNT - GB_PREP) * 64;
        for (int idx = t; idx < 64 * K; idx += 256) {
            int n = idx / K, k = idx - n * K;
            int g = n0 + n;
            xs[n][k] = (g < NN) ? xin[(size_t)g * K + k] : 0.f;
        }
        __syncthreads();
        int ng = t >> 4;
        int f0 = (t & 15) * 4;
        float acc[4][4] = {};
        for (int k = 0; k < K; ++k) {
            float4 w4 = *(const float4*)&W0[k * HD + f0];
            #pragma unroll
            for (int j = 0; j < 4; ++j) {
                float xv = xs[ng * 4 + j][k];
                acc[j][0] += xv * w4.x; acc[j][1] += xv * w4.y;
                acc[j][2] += xv * w4.z; acc[j][3] += xv * w4.w;
            }
        }
        float4 b4 = *(const float4*)&b0[f0];
        #pragma unroll
        for (int j = 0; j < 4; ++j) {
            int g = n0 + ng * 4 + j;
            if (g < NN) {
                float4 o;
                o.x = fmaxf(acc[j][0] + b4.x, 0.f);
                o.y = fmaxf(acc[j][1] + b4.y, 0.f);
                o.z = fmaxf(acc[j][2] + b4.z, 0.f);
                o.w = fmaxf(acc[j][3] + b4.w, 0.f);
                *(float4*)&x[(size_t)g * HD + f0] = o;
            }
        }
    }
}

// ---------------- scans (2 kernels) ----------------------------------------
__global__ __launch_bounds__(256) void scan_blk(
        const int* __restrict__ cnt, int* __restrict__ bsum) {
    __shared__ int s[256];
    int t = threadIdx.x;
    int i = blockIdx.x * 256 + t;
    int c = (i < NKEY) ? cnt[i] : 0;
    s[t] = c; __syncthreads();
    for (int d = 1; d < 256; d <<= 1) {
        int v = (t >= d) ? s[t - d] : 0;
        __syncthreads(); s[t] += v; __syncthreads();
    }
    if (t == 255) bsum[blockIdx.x] = s[255];
}

// per-block: recompute top-level exclusive prefix from bsum (<=4 loads/thread)
__global__ __launch_bounds__(256) void scan_fin2(
        const int* __restrict__ cnt, const int* __restrict__ bsum,
        int* __restrict__ ofs) {
    __shared__ int s[256];
    int t = threadIdx.x;
    int i = blockIdx.x * 256 + t;
    int pre = 0;
    for (int j = t; j < blockIdx.x; j += 256) pre += bsum[j];
    s[t] = pre; __syncthreads();
    for (int d = 128; d > 0; d >>= 1) {
        if (t < d) s[t] += s[t + d];
        __syncthreads();
    }
    int base = s[0];
    __syncthreads();
    int c = (i < NKEY) ? cnt[i] : 0;
    s[t] = c; __syncthreads();
    for (int d = 1; d < 256; d <<= 1) {
        int v = (t >= d) ? s[t - d] : 0;
        __syncthreads(); s[t] += v; __syncthreads();
    }
    if (i < NKEY) ofs[i] = base + s[t] - c;  // exclusive
}

// ---------------- u/v via MFMA, split-fp16, W direct from global -----------
// 64 nodes/block, 4 waves, wave w -> node rows w*16.. A-frag loaded straight
// from global (lane-private), split to h/l in regs. B-frags (W^T) read
// straight from global: per nt, 2 wave-loads cover 16 rows x 128B contiguous
// -> coalesced + L1/L2-hot across blocks. No barrier; LDS only for repack.
__device__ __forceinline__ void uv_body(
        UvLds& L, int bid, const float* __restrict__ x,
        const _Float16* __restrict__ Wuh, const _Float16* __restrict__ Wul,
        const _Float16* __restrict__ Wvh, const _Float16* __restrict__ Wvl,
        const float* __restrict__ bias,
        _Float16* __restrict__ u, _Float16* __restrict__ v) {
    int t = threadIdx.x;
    int n0 = bid * 64;
    int w = t >> 6, lane = t & 63;
    int quad = lane >> 4, l16 = lane & 15;
    int m0 = w * 16;
    int row = n0 + m0 + l16;
    // A-frags: lane-private, direct from global, split in regs
    half8 ah0, ah1, al0, al1;
    {
        float f[16];
        if (row < NN) {
            const float4* p = (const float4*)&x[(size_t)row * HD + quad * 8];
            *(float4*)&f[0] = p[0]; *(float4*)&f[4] = p[1];
            const float4* q = (const float4*)&x[(size_t)row * HD + 32 + quad * 8];
            *(float4*)&f[8] = q[0]; *(float4*)&f[12] = q[1];
        } else {
            #pragma unroll
            for (int j = 0; j < 16; ++j) f[j] = 0.f;
        }
        #pragma unroll
        for (int j = 0; j < 8; ++j) {
            _Float16 h = (_Float16)f[j];
            ah0[j] = h; al0[j] = (_Float16)(f[j] - (float)h);
            _Float16 h2 = (_Float16)f[j + 8];
            ah1[j] = h2; al1[j] = (_Float16)(f[j + 8] - (float)h2);
        }
    }

    float4v au[4], av[4];
    #pragma unroll
    for (int nt = 0; nt < 4; ++nt) {
        int n = nt * 16 + l16;
        half8 bh0 = *(const half8*)&Wuh[n * 64 + quad * 8];
        half8 bh1 = *(const half8*)&Wuh[n * 64 + 32 + quad * 8];
        half8 bl0 = *(const half8*)&Wul[n * 64 + quad * 8];
        half8 bl1 = *(const half8*)&Wul[n * 64 + 32 + quad * 8];
        float4v acc = {0.f, 0.f, 0.f, 0.f};
        acc = __builtin_amdgcn_mfma_f32_16x16x32_f16(ah0, bh0, acc, 0, 0, 0);
        acc = __builtin_amdgcn_mfma_f32_16x16x32_f16(ah1, bh1, acc, 0, 0, 0);
        acc = __builtin_amdgcn_mfma_f32_16x16x32_f16(al0, bh0, acc, 0, 0, 0);
        acc = __builtin_amdgcn_mfma_f32_16x16x32_f16(al1, bh1, acc, 0, 0, 0);
        acc = __builtin_amdgcn_mfma_f32_16x16x32_f16(ah0, bl0, acc, 0, 0, 0);
        acc = __builtin_amdgcn_mfma_f32_16x16x32_f16(ah1, bl1, acc, 0, 0, 0);
        au[nt] = acc;
        half8 ch0 = *(const half8*)&Wvh[n * 64 + quad * 8];
        half8 ch1 = *(const half8*)&Wvh[n * 64 + 32 + quad * 8];
        half8 cl0 = *(const half8*)&Wvl[n * 64 + quad * 8];
        half8 cl1 = *(const half8*)&Wvl[n * 64 + 32 + quad * 8];
        float4v accv = {0.f, 0.f, 0.f, 0.f};
        accv = __builtin_amdgcn_mfma_f32_16x16x32_f16(ah0, ch0, accv, 0, 0, 0);
        accv = __builtin_amdgcn_mfma_f32_16x16x32_f16(ah1, ch1, accv, 0, 0, 0);
        accv = __builtin_amdgcn_mfma_f32_16x16x32_f16(al0, ch0, accv, 0, 0, 0);
        accv = __builtin_amdgcn_mfma_f32_16x16x32_f16(al1, ch1, accv, 0, 0, 0);
        accv = __builtin_amdgcn_mfma_f32_16x16x32_f16(ah0, cl0, accv, 0, 0, 0);
        accv = __builtin_amdgcn_mfma_f32_16x16x32_f16(ah1, cl1, accv, 0, 0, 0);
        av[nt] = accv;
    }

    // repack u (+bias) through per-wave LDS, store 16B vectors
    _Float16* rpw = &L.rp[w * 16 * 72];
    #pragma unroll
    for (int nt = 0; nt < 4; ++nt) {
        float bn = bias[nt * 16 + l16];
        #pragma unroll
        for (int r = 0; r < 4; ++r)
            rpw[(quad * 4 + r) * 72 + nt * 16 + l16] = (_Float16)(au[nt][r] + bn);
    }
    int mr = lane >> 2, cr = (lane & 3) * 16;
    int gr = n0 + m0 + mr;
    if (gr < NN) {
        *(half8*)&u[(size_t)gr * HD + cr]     = *(half8*)&rpw[mr * 72 + cr];
        *(half8*)&u[(size_t)gr * HD + cr + 8] = *(half8*)&rpw[mr * 72 + cr + 8];
    }
    // repack v (DS pipe is in-order per wave: prior reads complete first)
    #pragma unroll
    for (int nt = 0; nt < 4; ++nt) {
        #pragma unroll
        for (int r = 0; r < 4; ++r)
            rpw[(quad * 4 + r) * 72 + nt * 16 + l16] = (_Float16)(av[nt][r]);
    }
    if (gr < NN) {
        *(half8*)&v[(size_t)gr * HD + cr]     = *(half8*)&rpw[mr * 72 + cr];
        *(half8*)&v[(size_t)gr * HD + cr + 8] = *(half8*)&rpw[mr * 72 + cr + 8];
    }
}

__global__ __launch_bounds__(256) void uv_slim(
        const float* __restrict__ x,
        const _Float16* __restrict__ Wuh, const _Float16* __restrict__ Wul,
        const _Float16* __restrict__ Wvh, const _Float16* __restrict__ Wvl,
        const float* __restrict__ bias,
        _Float16* __restrict__ u, _Float16* __restrict__ v) {
    __shared__ UvLds L;
    uv_body(L, blockIdx.x, x, Wuh, Wul, Wvh, Wvl, bias, u, v);
}

// ---------------- fill + first uv fused ------------------------------------
__global__ __launch_bounds__(256) void k_fill_uv(
        const int* __restrict__ ei, const float* __restrict__ ef,
        const int* __restrict__ ofs, const uchar2* __restrict__ rank,
        unsigned* __restrict__ em_val, int* __restrict__ ec_val,
        const float* __restrict__ x,
        const _Float16* __restrict__ Wuh, const _Float16* __restrict__ Wul,
        const _Float16* __restrict__ Wvh, const _Float16* __restrict__ Wvl,
        const float* __restrict__ bias,
        _Float16* __restrict__ u, _Float16* __restrict__ v) {
    __shared__ UvLds L;
    if (blockIdx.x < GB_CNT) {
        // fill (no atomics): em value = dst<<16 | fp16(ef) bits; ec value = src
        int e = blockIdx.x * 256 + threadIdx.x;   // grid exact: e < NE
        int src = ei[e];
        int dst = ei[NE + e];
        int o = e / PER;
        uchar2 r = rank[e];
        int p1 = ofs[o * NN + src] + r.x;
        unsigned short eb = __half_as_ushort(__float2half_rn(ef[e]));
        em_val[p1] = ((unsigned)dst << 16) | (unsigned)eb;
        int p2 = ofs[4 * NN + dst] + r.y - NE;
        ec_val[p2] = src;
    } else {
        uv_body(L, blockIdx.x - GB_CNT, x, Wuh, Wul, Wvh, Wvl, bias, u, v);
    }
}

// load 8 consecutive halves (16B aligned) -> 8 floats
__device__ __forceinline__ void load_h8(const __half* p, float* o) {
    float4 r = *(const float4*)p;
    __half2 h0 = *reinterpret_cast<__half2*>(&r.x);
    __half2 h1 = *reinterpret_cast<__half2*>(&r.y);
    __half2 h2 = *reinterpret_cast<__half2*>(&r.z);
    __half2 h3 = *reinterpret_cast<__half2*>(&r.w);
    float2 f0 = __half22float2(h0), f1 = __half22float2(h1);
    float2 f2 = __half22float2(h2), f3 = __half22float2(h3);
    o[0] = f0.x; o[1] = f0.y; o[2] = f1.x; o[3] = f1.y;
    o[4] = f2.x; o[5] = f2.y; o[6] = f3.x; o[7] = f3.y;
}

// ---------------- emulsion edge pass + fold --------------------------------
// 8 nodes/wave, 8 lanes/node, 8 features/lane. 4-wide unroll: 4 independent
// 16B gathers in flight per lane (latency-bound; halves serial chain).
// x[n] = (x[n] + sum_e relu(u[dst]+v[n]+ef*we)) / 2   (node-local update)
__global__ __launch_bounds__(256) void em_edge(
        const unsigned* __restrict__ em_val, const int* __restrict__ ofs,
        const __half* __restrict__ u, const __half* __restrict__ v,
        const float* __restrict__ we, float* __restrict__ x, int order) {
    int t = threadIdx.x;
    int node = blockIdx.x * 32 + (t >> 3);
    if (node >= NN) return;
    int f0 = (t & 7) * 8;
    int key = order * NN + node;
    int s0 = ofs[key], s1 = ofs[key + 1];
    float vn[8], wef[8], acc[8] = {};
    load_h8(&v[(size_t)node * HD + f0], vn);
    *(float4*)&wef[0] = *(const float4*)&we[f0];
    *(float4*)&wef[4] = *(const float4*)&we[f0 + 4];
    int p = s0;
    for (; p + 4 <= s1; p += 4) {
        unsigned e0 = em_val[p], e1 = em_val[p + 1];
        unsigned e2 = em_val[p + 2], e3 = em_val[p + 3];
        float u0[8], u1[8], u2[8], u3[8];
        load_h8(&u[(size_t)(e0 >> 16) * HD + f0], u0);
        load_h8(&u[(size_t)(e1 >> 16) * HD + f0], u1);
        load_h8(&u[(size_t)(e2 >> 16) * HD + f0], u2);
        load_h8(&u[(size_t)(e3 >> 16) * HD + f0], u3);
        float ef0 = __half2float(__ushort_as_half((unsigned short)(e0 & 0xffff)));
        float ef1 = __half2float(__ushort_as_half((unsigned short)(e1 & 0xffff)));
        float ef2 = __half2float(__ushort_as_half((unsigned short)(e2 & 0xffff)));
        float ef3 = __half2float(__ushort_as_half((unsigned short)(e3 & 0xffff)));
        #pragma unroll
        for (int j = 0; j < 8; ++j) {
            acc[j] += fmaxf(u0[j] + vn[j] + ef0 * wef[j], 0.f)
                    + fmaxf(u1[j] + vn[j] + ef1 * wef[j], 0.f)
                    + fmaxf(u2[j] + vn[j] + ef2 * wef[j], 0.f)
                    + fmaxf(u3[j] + vn[j] + ef3 * wef[j], 0.f);
        }
    }
    if (p + 2 <= s1) {
        unsigned e0 = em_val[p], e1 = em_val[p + 1];
        float u0[8], u1[8];
        load_h8(&u[(size_t)(e0 >> 16) * HD + f0], u0);
        load_h8(&u[(size_t)(e1 >> 16) * HD + f0], u1);
        float ef0 = __half2float(__ushort_as_half((unsigned short)(e0 & 0xffff)));
        float ef1 = __half2float(__ushort_as_half((unsigned short)(e1 & 0xffff)));
        #pragma unroll
        for (int j = 0; j < 8; ++j) {
            acc[j] += fmaxf(u0[j] + vn[j] + ef0 * wef[j], 0.f)
                    + fmaxf(u1[j] + vn[j] + ef1 * wef[j], 0.f);
        }
        p += 2;
    }
    if (p < s1) {
        unsigned e0 = em_val[p];
        float u0[8];
        load_h8(&u[(size_t)(e0 >> 16) * HD + f0], u0);
        float ef0 = __half2float(__ushort_as_half((unsigned short)(e0 & 0xffff)));
        #pragma unroll
        for (int j = 0; j < 8; ++j)
            acc[j] += fmaxf(u0[j] + vn[j] + ef0 * wef[j], 0.f);
    }
    float xr[8];
    *(float4*)&xr[0] = *(const float4*)&x[(size_t)node * HD + f0];
    *(float4*)&xr[4] = *(const float4*)&x[(size_t)node * HD + f0 + 4];
    #pragma unroll
    for (int j = 0; j < 8; ++j) xr[j] = (xr[j] + acc[j]) * 0.5f;
    *(float4*)&x[(size_t)node * HD + f0] = *(float4*)&xr[0];
    *(float4*)&x[(size_t)node * HD + f0 + 4] = *(float4*)&xr[4];
}

// ---------------- edge conv pass -------------------------------------------
// max_e relu(u[n]+v[src]) == relu(u[n] + max_e v[src])  (fp-exact: max
// commutes with monotone add); empty segment -> 0. 4-wide unroll.
__global__ __launch_bounds__(256) void ec_edge(
        const int* __restrict__ ec_val, const int* __restrict__ ofs,
        const __half* __restrict__ u, const __half* __restrict__ v,
        float* __restrict__ x) {
    int t = threadIdx.x;
    int node = blockIdx.x * 32 + (t >> 3);
    if (node >= NN) return;
    int f0 = (t & 7) * 8;
    int s0 = ofs[4 * NN + node] - NE, s1 = ofs[4 * NN + node + 1] - NE;
    float o[8];
    if (s1 > s0) {
        float m[8];
        #pragma unroll
        for (int j = 0; j < 8; ++j) m[j] = -3.0e38f;
        int p = s0;
        for (; p + 4 <= s1; p += 4) {
            int i0 = ec_val[p], i1 = ec_val[p + 1];
            int i2 = ec_val[p + 2], i3 = ec_val[p + 3];
            float v0[8], v1[8], v2[8], v3[8];
            load_h8(&v[(size_t)i0 * HD + f0], v0);
            load_h8(&v[(size_t)i1 * HD + f0], v1);
            load_h8(&v[(size_t)i2 * HD + f0], v2);
            load_h8(&v[(size_t)i3 * HD + f0], v3);
            #pragma unroll
            for (int j = 0; j < 8; ++j)
                m[j] = fmaxf(fmaxf(m[j], fmaxf(v0[j], v1[j])),
                             fmaxf(v2[j], v3[j]));
        }
        if (p + 2 <= s1) {
            int i0 = ec_val[p], i1 = ec_val[p + 1];
            float v0[8], v1[8];
            load_h8(&v[(size_t)i0 * HD + f0], v0);
            load_h8(&v[(size_t)i1 * HD + f0], v1);
            #pragma unroll
            for (int j = 0; j < 8; ++j)
                m[j] = fmaxf(m[j], fmaxf(v0[j], v1[j]));
            p += 2;
        }
        if (p < s1) {
            int i0 = ec_val[p];
            float v0[8];
            load_h8(&v[(size_t)i0 * HD + f0], v0);
            #pragma unroll
            for (int j = 0; j < 8; ++j) m[j] = fmaxf(m[j], v0[j]);
        }
        float un[8];
        load_h8(&u[(size_t)node * HD + f0], un);
        #pragma unroll
        for (int j = 0; j < 8; ++j) o[j] = fmaxf(un[j] + m[j], 0.f);
    } else {
        #pragma unroll
        for (int j = 0; j < 8; ++j) o[j] = 0.f;
    }
    *(float4*)&x[(size_t)node * HD + f0] = *(float4*)&o[0];
    *(float4*)&x[(size_t)node * HD + f0 + 4] = *(float4*)&o[4];
}

// ---------------- linear: x = relu(x @ W + b), scalar fp32 ------------------
template<int K>
__global__ __launch_bounds__(256) void lin_kernel(
        const float* __restrict__ xin,
        const float* __restrict__ W, const float* __restrict__ bias,
        float* __restrict__ xout) {
    __shared__ float xs[64][K + 1];
    int t = threadIdx.x;
    int n0 = blockIdx.x * 64;
    for (int idx = t; idx < 64 * K; idx += 256) {
        int n = idx / K, k = idx - n * K;
        int g = n0 + n;
        xs[n][k] = (g < NN) ? xin[(size_t)g * K + k] : 0.f;
    }
    __syncthreads();
    int ng = t >> 4;
    int f0 = (t & 15) * 4;
    float acc[4][4] = {};
    for (int k = 0; k < K; ++k) {
        float4 w4 = *(const float4*)&W[k * HD + f0];
        #pragma unroll
        for (int j = 0; j < 4; ++j) {
            float xv = xs[ng * 4 + j][k];
            acc[j][0] += xv * w4.x; acc[j][1] += xv * w4.y;
            acc[j][2] += xv * w4.z; acc[j][3] += xv * w4.w;
        }
    }
    float4 b4 = *(const float4*)&bias[f0];
    #pragma unroll
    for (int j = 0; j < 4; ++j) {
        int g = n0 + ng * 4 + j;
        if (g < NN) {
            float4 o;
            o.x = fmaxf(acc[j][0] + b4.x, 0.f);
            o.y = fmaxf(acc[j][1] + b4.y, 0.f);
            o.z = fmaxf(acc[j][2] + b4.z, 0.f);
            o.w = fmaxf(acc[j][3] + b4.w, 0.f);
            *(float4*)&xout[(size_t)g * HD + f0] = o;
        }
    }
}

// ---------------- output projection ----------------------------------------
__global__ __launch_bounds__(256) void out_kernel(
        const float* __restrict__ x, const float* __restrict__ W,
        const float* __restrict__ bias, float* __restrict__ out) {
    int n = blockIdx.x * 256 + threadIdx.x;
    if (n >= NN) return;
    float xr[HD];
    #pragma unroll
    for (int k = 0; k < HD; k += 4) {
        float4 t4 = *(const float4*)&x[(size_t)n * HD + k];
        xr[k] = t4.x; xr[k + 1] = t4.y; xr[k + 2] = t4.z; xr[k + 3] = t4.w;
    }
    #pragma unroll
    for (int f = 0; f < 10; ++f) {
        float acc = bias[f];
        #pragma unroll
        for (int k = 0; k < HD; ++k) acc += xr[k] * W[k * 10 + f];
        out[(size_t)n * 10 + f] = acc;
    }
}

extern "C" void kernel_launch(void* const* d_in, const int* in_sizes, int n_in,
                              void* d_out, int out_size, void* d_ws, size_t ws_size,
                              hipStream_t stream) {
    const float* x_in  = (const float*)d_in[0];
    const int*   ei    = (const int*)d_in[1];
    const float* ef    = (const float*)d_in[2];
    const float* lw[3] = {(const float*)d_in[3], (const float*)d_in[5], (const float*)d_in[7]};
    const float* lb[3] = {(const float*)d_in[4], (const float*)d_in[6], (const float*)d_in[8]};
    const float* em_w  = (const float*)d_in[9];
    const float* em_b  = (const float*)d_in[10];
    const float* ec_w  = (const float*)d_in[11];
    const float* ec_b  = (const float*)d_in[12];
    const float* ow    = (const float*)d_in[13];
    const float* ob    = (const float*)d_in[14];
    float* out = (float*)d_out;

    char* wsb = (char*)d_ws;
    size_t off = 0;
    auto alloc = [&](size_t bytes) {
        void* p = wsb + off;
        off = (off + bytes + 255) & ~(size_t)255;
        return p;
    };
    float*     x      = (float*)alloc((size_t)NN * HD * 4);
    _Float16*  u      = (_Float16*)alloc((size_t)NN * HD * 2);
    _Float16*  v      = (_Float16*)alloc((size_t)NN * HD * 2);
    int*       cnt    = (int*)alloc((size_t)NKEY * 4);
    int*       ofs    = (int*)alloc((size_t)NKEY * 4);
    int*       bsum   = (int*)alloc((size_t)1024 * 4);
    uchar2*    rank   = (uchar2*)alloc((size_t)NE * 2);
    unsigned*  em_val = (unsigned*)alloc((size_t)NE * 4);
    int*       ec_val = (int*)alloc((size_t)NE * 4);
    _Float16*  wh     = (_Float16*)alloc((size_t)24 * 4096 * 2);
    (void)ws_size; (void)in_sizes; (void)n_in; (void)out_size;

    const int gb_n8 = (NN + 31) / 32;   // 1563

    // ---- CSR build + weight prep + lin0 (fused front) ----
    hipMemsetAsync(cnt, 0, (size_t)NKEY * 4, stream);
    k_front<<<GB_CNT + GB_PREP + GB_LIN, 256, 0, stream>>>(
        ei, cnt, rank, em_w, ec_w, wh, x_in, lw[0], lb[0], x);
    scan_blk<<<GB_KEYS, 256, 0, stream>>>(cnt, bsum);
    scan_fin2<<<GB_KEYS, 256, 0, stream>>>(cnt, bsum, ofs);

    // fill fused with layer-0/order-0 uv GEMM
    k_fill_uv<<<GB_CNT + GB_LIN, 256, 0, stream>>>(
        ei, ef, ofs, rank, em_val, ec_val, x,
        wh, wh + (size_t)12 * 4096, wh + (size_t)3 * 4096, wh + (size_t)15 * 4096,
        em_b, u, v);

    // ---- network ----
    for (int i = 0; i < 3; ++i) {
        const _Float16* Wuh = wh + (size_t)i * 4096;
        const _Float16* Wvh = wh + (size_t)(3 + i) * 4096;
        const _Float16* Wul = wh + (size_t)(12 + i) * 4096;
        const _Float16* Wvl = wh + (size_t)(15 + i) * 4096;
        const float* bi = em_b + (size_t)i * HD;
        const float* we = em_w + (size_t)i * 129 * HD + 128 * HD;
        for (int o = 0; o < 4; ++o) {
            if (!(i == 0 && o == 0))
                uv_slim<<<GB_LIN, 256, 0, stream>>>(x, Wuh, Wul, Wvh, Wvl, bi, u, v);
            em_edge<<<gb_n8, 256, 0, stream>>>(em_val, ofs, (const __half*)u,
                                               (const __half*)v, we, x, o);
        }
        if (i < 2)
            lin_kernel<64><<<GB_LIN, 256, 0, stream>>>(x, lw[i + 1], lb[i + 1], x);
    }

    for (int j = 0; j < 3; ++j) {
        const _Float16* Wuh = wh + (size_t)(6 + j) * 4096;
        const _Float16* Wvh = wh + (size_t)(9 + j) * 4096;
        const _Float16* Wul = wh + (size_t)(18 + j) * 4096;
        const _Float16* Wvl = wh + (size_t)(21 + j) * 4096;
        const float* bj = ec_b + (size_t)j * HD;
        uv_slim<<<GB_LIN, 256, 0, stream>>>(x, Wuh, Wul, Wvh, Wvl, bj, u, v);
        ec_edge<<<gb_n8, 256, 0, stream>>>(ec_val, ofs, (const __half*)u,
                                           (const __half*)v, x);
    }

    out_kernel<<<(NN + 255) / 256, 256, 0, stream>>>(x, ow, ob, out);
}

// Round 3
// 567.602 us; speedup vs baseline: 1.2907x; 1.2907x over previous
//
#include <hip/hip_runtime.h>
#include <hip/hip_fp16.h>

// GraphNN_KNN: N=50000 nodes, E=800000 edges, H=64.
// msg = relu([x_i, x_j-x_i, ef] @ W + b) == relu(u[dst] + v[src] + ef*we)
// with u = x@(Wt-Wm)+b, v = x@Wm. u/v GEMMs use MFMA 16x16x32_f16 with
// split-fp16 inputs (3 product terms) for fp32-level accuracy; outputs fp16.
// Round 3: revert round-2 regressions (W back in LDS for uv; 2-wide gather
// width). NEW: software-pipelined gathers in em_edge/ec_edge — prefetch the
// next edge-pair's index+128B row while consuming the current pair. Pipeline
// regs are raw float4 (VGPR stays <=64 -> 8 waves/SIMD preserved).

#define NN 50000
#define NE 800000
#define PER 200000      // E / 4 orders
#define HD 64
#define NKEY 250112     // 4*NN em keys + NN ec keys, padded to 977*256
#define GB_CNT 3125     // NE/256
#define GB_PREP 192     // 12*4096/256
#define GB_LIN 782      // ceil(NN/64)
#define GB_KEYS 977     // NKEY/256

typedef _Float16 half8 __attribute__((ext_vector_type(8)));
typedef float float4v __attribute__((ext_vector_type(4)));

struct UvLds {
    _Float16 wuh[64 * 72], wul[64 * 72], wvh[64 * 72], wvl[64 * 72];
    _Float16 rp[4 * 16 * 72];
};

// ---------------- front mega-kernel: count | prep_w | lin0 -----------------
__global__ __launch_bounds__(256) void k_front(
        const int* __restrict__ ei, int* __restrict__ cnt,
        uchar2* __restrict__ rank,
        const float* __restrict__ em_w, const float* __restrict__ ec_w,
        _Float16* __restrict__ wh,
        const float* __restrict__ xin, const float* __restrict__ W0,
        const float* __restrict__ b0, float* __restrict__ x) {
    __shared__ float xs[64][11];
    int t = threadIdx.x;
    if (blockIdx.x < GB_CNT) {
        // ---- count (atomic histogram + rank capture) ----
        int e = blockIdx.x * 256 + t;           // grid exact: e < NE
        int src = ei[e];
        int dst = ei[NE + e];
        int o = e / PER;
        int r1 = atomicAdd(&cnt[o * NN + src], 1);
        int r2 = atomicAdd(&cnt[4 * NN + dst], 1);
        rank[e] = make_uchar2((unsigned char)r1, (unsigned char)r2);
    } else if (blockIdx.x < GB_CNT + GB_PREP) {
        // ---- weight prep: split-fp16, transposed [n][k] ----
        // mats 0-2 emWu, 3-5 emWv, 6-8 ecWu, 9-11 ecWv; lo parts at +12.
        int idx = (blockIdx.x - GB_CNT) * 256 + t;   // < 12*4096
        int mat = idx >> 12, pos = idx & 4095;
        int n = pos >> 6, k = pos & 63;
        float val;
        if (mat < 3)      { const float* B = em_w + mat * 129 * 64;     val = B[k*64+n] - B[(64+k)*64+n]; }
        else if (mat < 6) { const float* B = em_w + (mat-3) * 129 * 64; val = B[(64+k)*64+n]; }
        else if (mat < 9) { const float* B = ec_w + (mat-6) * 128 * 64; val = B[k*64+n] - B[(64+k)*64+n]; }
        else              { const float* B = ec_w + (mat-9) * 128 * 64; val = B[(64+k)*64+n]; }
        _Float16 h = (_Float16)val;
        _Float16 l = (_Float16)(val - (float)h);
        wh[(size_t)mat * 4096 + n * 64 + k] = h;
        wh[(size_t)(12 + mat) * 4096 + n * 64 + k] = l;
    } else {
        // ---- lin0: x = relu(xin @ W0 + b0), K=10 ----
        const int K = 10;
        int n0 = (blockIdx.x - GB_CNT - GB_PREP) * 64;
        for (int idx = t; idx < 64 * K; idx += 256) {
            int n = idx / K, k = idx - n * K;
            int g = n0 + n;
            xs[n][k] = (g < NN) ? xin[(size_t)g * K + k] : 0.f;
        }
        __syncthreads();
        int ng = t >> 4;
        int f0 = (t & 15) * 4;
        float acc[4][4] = {};
        for (int k = 0; k < K; ++k) {
            float4 w4 = *(const float4*)&W0[k * HD + f0];
            #pragma unroll
            for (int j = 0; j < 4; ++j) {
                float xv = xs[ng * 4 + j][k];
                acc[j][0] += xv * w4.x; acc[j][1] += xv * w4.y;
                acc[j][2] += xv * w4.z; acc[j][3] += xv * w4.w;
            }
        }
        float4 b4 = *(const float4*)&b0[f0];
        #pragma unroll
        for (int j = 0; j < 4; ++j) {
            int g = n0 + ng * 4 + j;
            if (g < NN) {
                float4 o;
                o.x = fmaxf(acc[j][0] + b4.x, 0.f);
                o.y = fmaxf(acc[j][1] + b4.y, 0.f);
                o.z = fmaxf(acc[j][2] + b4.z, 0.f);
                o.w = fmaxf(acc[j][3] + b4.w, 0.f);
                *(float4*)&x[(size_t)g * HD + f0] = o;
            }
        }
    }
}

// ---------------- scans (2 kernels) ----------------------------------------
__global__ __launch_bounds__(256) void scan_blk(
        const int* __restrict__ cnt, int* __restrict__ bsum) {
    __shared__ int s[256];
    int t = threadIdx.x;
    int i = blockIdx.x * 256 + t;
    int c = (i < NKEY) ? cnt[i] : 0;
    s[t] = c; __syncthreads();
    for (int d = 1; d < 256; d <<= 1) {
        int v = (t >= d) ? s[t - d] : 0;
        __syncthreads(); s[t] += v; __syncthreads();
    }
    if (t == 255) bsum[blockIdx.x] = s[255];
}

// per-block: recompute top-level exclusive prefix from bsum (<=4 loads/thread)
__global__ __launch_bounds__(256) void scan_fin2(
        const int* __restrict__ cnt, const int* __restrict__ bsum,
        int* __restrict__ ofs) {
    __shared__ int s[256];
    int t = threadIdx.x;
    int i = blockIdx.x * 256 + t;
    int pre = 0;
    for (int j = t; j < blockIdx.x; j += 256) pre += bsum[j];
    s[t] = pre; __syncthreads();
    for (int d = 128; d > 0; d >>= 1) {
        if (t < d) s[t] += s[t + d];
        __syncthreads();
    }
    int base = s[0];
    __syncthreads();
    int c = (i < NKEY) ? cnt[i] : 0;
    s[t] = c; __syncthreads();
    for (int d = 1; d < 256; d <<= 1) {
        int v = (t >= d) ? s[t - d] : 0;
        __syncthreads(); s[t] += v; __syncthreads();
    }
    if (i < NKEY) ofs[i] = base + s[t] - c;  // exclusive
}

// ---------------- u/v via MFMA, split-fp16 ---------------------------------
// 64 nodes/block, 4 waves. A-frags lane-private straight from global; W in
// LDS (round-1 layout: shared by all waves, 72-padded); rp for output repack.
__device__ __forceinline__ void uv_body(
        UvLds& L, int bid, const float* __restrict__ x,
        const _Float16* __restrict__ Wuh, const _Float16* __restrict__ Wul,
        const _Float16* __restrict__ Wvh, const _Float16* __restrict__ Wvl,
        const float* __restrict__ bias,
        _Float16* __restrict__ u, _Float16* __restrict__ v) {
    int t = threadIdx.x;
    int n0 = bid * 64;
    { // stage W (4 arrays), row remap into 72-padded LDS
        int n = t >> 2, c = (t & 3) * 16;
        *(half8*)&L.wuh[n * 72 + c]     = *(const half8*)&Wuh[n * 64 + c];
        *(half8*)&L.wuh[n * 72 + c + 8] = *(const half8*)&Wuh[n * 64 + c + 8];
        *(half8*)&L.wul[n * 72 + c]     = *(const half8*)&Wul[n * 64 + c];
        *(half8*)&L.wul[n * 72 + c + 8] = *(const half8*)&Wul[n * 64 + c + 8];
        *(half8*)&L.wvh[n * 72 + c]     = *(const half8*)&Wvh[n * 64 + c];
        *(half8*)&L.wvh[n * 72 + c + 8] = *(const half8*)&Wvh[n * 64 + c + 8];
        *(half8*)&L.wvl[n * 72 + c]     = *(const half8*)&Wvl[n * 64 + c];
        *(half8*)&L.wvl[n * 72 + c + 8] = *(const half8*)&Wvl[n * 64 + c + 8];
    }
    int w = t >> 6, lane = t & 63;
    int quad = lane >> 4, l16 = lane & 15;
    int m0 = w * 16;
    int row = n0 + m0 + l16;
    // A-frags: lane-private, direct from global, split in regs
    half8 ah0, ah1, al0, al1;
    {
        float f[16];
        if (row < NN) {
            const float4* p = (const float4*)&x[(size_t)row * HD + quad * 8];
            *(float4*)&f[0] = p[0]; *(float4*)&f[4] = p[1];
            const float4* q = (const float4*)&x[(size_t)row * HD + 32 + quad * 8];
            *(float4*)&f[8] = q[0]; *(float4*)&f[12] = q[1];
        } else {
            #pragma unroll
            for (int j = 0; j < 16; ++j) f[j] = 0.f;
        }
        #pragma unroll
        for (int j = 0; j < 8; ++j) {
            _Float16 h = (_Float16)f[j];
            ah0[j] = h; al0[j] = (_Float16)(f[j] - (float)h);
            _Float16 h2 = (_Float16)f[j + 8];
            ah1[j] = h2; al1[j] = (_Float16)(f[j + 8] - (float)h2);
        }
    }
    __syncthreads();

    float4v au[4], av[4];
    #pragma unroll
    for (int nt = 0; nt < 4; ++nt) {
        int n = nt * 16 + l16;
        half8 bh0 = *(half8*)&L.wuh[n * 72 + quad * 8];
        half8 bh1 = *(half8*)&L.wuh[n * 72 + 32 + quad * 8];
        half8 bl0 = *(half8*)&L.wul[n * 72 + quad * 8];
        half8 bl1 = *(half8*)&L.wul[n * 72 + 32 + quad * 8];
        float4v acc = {0.f, 0.f, 0.f, 0.f};
        acc = __builtin_amdgcn_mfma_f32_16x16x32_f16(ah0, bh0, acc, 0, 0, 0);
        acc = __builtin_amdgcn_mfma_f32_16x16x32_f16(ah1, bh1, acc, 0, 0, 0);
        acc = __builtin_amdgcn_mfma_f32_16x16x32_f16(al0, bh0, acc, 0, 0, 0);
        acc = __builtin_amdgcn_mfma_f32_16x16x32_f16(al1, bh1, acc, 0, 0, 0);
        acc = __builtin_amdgcn_mfma_f32_16x16x32_f16(ah0, bl0, acc, 0, 0, 0);
        acc = __builtin_amdgcn_mfma_f32_16x16x32_f16(ah1, bl1, acc, 0, 0, 0);
        au[nt] = acc;
        half8 ch0 = *(half8*)&L.wvh[n * 72 + quad * 8];
        half8 ch1 = *(half8*)&L.wvh[n * 72 + 32 + quad * 8];
        half8 cl0 = *(half8*)&L.wvl[n * 72 + quad * 8];
        half8 cl1 = *(half8*)&L.wvl[n * 72 + 32 + quad * 8];
        float4v accv = {0.f, 0.f, 0.f, 0.f};
        accv = __builtin_amdgcn_mfma_f32_16x16x32_f16(ah0, ch0, accv, 0, 0, 0);
        accv = __builtin_amdgcn_mfma_f32_16x16x32_f16(ah1, ch1, accv, 0, 0, 0);
        accv = __builtin_amdgcn_mfma_f32_16x16x32_f16(al0, ch0, accv, 0, 0, 0);
        accv = __builtin_amdgcn_mfma_f32_16x16x32_f16(al1, ch1, accv, 0, 0, 0);
        accv = __builtin_amdgcn_mfma_f32_16x16x32_f16(ah0, cl0, accv, 0, 0, 0);
        accv = __builtin_amdgcn_mfma_f32_16x16x32_f16(ah1, cl1, accv, 0, 0, 0);
        av[nt] = accv;
    }

    // repack u (+bias) through per-wave LDS, store 16B vectors
    _Float16* rpw = &L.rp[w * 16 * 72];
    #pragma unroll
    for (int nt = 0; nt < 4; ++nt) {
        float bn = bias[nt * 16 + l16];
        #pragma unroll
        for (int r = 0; r < 4; ++r)
            rpw[(quad * 4 + r) * 72 + nt * 16 + l16] = (_Float16)(au[nt][r] + bn);
    }
    int mr = lane >> 2, cr = (lane & 3) * 16;
    int gr = n0 + m0 + mr;
    if (gr < NN) {
        *(half8*)&u[(size_t)gr * HD + cr]     = *(half8*)&rpw[mr * 72 + cr];
        *(half8*)&u[(size_t)gr * HD + cr + 8] = *(half8*)&rpw[mr * 72 + cr + 8];
    }
    // repack v (DS pipe is in-order per wave: prior reads complete first)
    #pragma unroll
    for (int nt = 0; nt < 4; ++nt) {
        #pragma unroll
        for (int r = 0; r < 4; ++r)
            rpw[(quad * 4 + r) * 72 + nt * 16 + l16] = (_Float16)(av[nt][r]);
    }
    if (gr < NN) {
        *(half8*)&v[(size_t)gr * HD + cr]     = *(half8*)&rpw[mr * 72 + cr];
        *(half8*)&v[(size_t)gr * HD + cr + 8] = *(half8*)&rpw[mr * 72 + cr + 8];
    }
}

__global__ __launch_bounds__(256) void uv_slim(
        const float* __restrict__ x,
        const _Float16* __restrict__ Wuh, const _Float16* __restrict__ Wul,
        const _Float16* __restrict__ Wvh, const _Float16* __restrict__ Wvl,
        const float* __restrict__ bias,
        _Float16* __restrict__ u, _Float16* __restrict__ v) {
    __shared__ UvLds L;
    uv_body(L, blockIdx.x, x, Wuh, Wul, Wvh, Wvl, bias, u, v);
}

// ---------------- fill + first uv fused ------------------------------------
__global__ __launch_bounds__(256) void k_fill_uv(
        const int* __restrict__ ei, const float* __restrict__ ef,
        const int* __restrict__ ofs, const uchar2* __restrict__ rank,
        unsigned* __restrict__ em_val, int* __restrict__ ec_val,
        const float* __restrict__ x,
        const _Float16* __restrict__ Wuh, const _Float16* __restrict__ Wul,
        const _Float16* __restrict__ Wvh, const _Float16* __restrict__ Wvl,
        const float* __restrict__ bias,
        _Float16* __restrict__ u, _Float16* __restrict__ v) {
    __shared__ UvLds L;
    if (blockIdx.x < GB_CNT) {
        // fill (no atomics): em value = dst<<16 | fp16(ef) bits; ec value = src
        int e = blockIdx.x * 256 + threadIdx.x;   // grid exact: e < NE
        int src = ei[e];
        int dst = ei[NE + e];
        int o = e / PER;
        uchar2 r = rank[e];
        int p1 = ofs[o * NN + src] + r.x;
        unsigned short eb = __half_as_ushort(__float2half_rn(ef[e]));
        em_val[p1] = ((unsigned)dst << 16) | (unsigned)eb;
        int p2 = ofs[4 * NN + dst] + r.y - NE;
        ec_val[p2] = src;
    } else {
        uv_body(L, blockIdx.x - GB_CNT, x, Wuh, Wul, Wvh, Wvl, bias, u, v);
    }
}

// load 8 consecutive halves (16B aligned) -> 8 floats
__device__ __forceinline__ void load_h8(const __half* p, float* o) {
    float4 r = *(const float4*)p;
    __half2 h0 = *reinterpret_cast<__half2*>(&r.x);
    __half2 h1 = *reinterpret_cast<__half2*>(&r.y);
    __half2 h2 = *reinterpret_cast<__half2*>(&r.z);
    __half2 h3 = *reinterpret_cast<__half2*>(&r.w);
    float2 f0 = __half22float2(h0), f1 = __half22float2(h1);
    float2 f2 = __half22float2(h2), f3 = __half22float2(h3);
    o[0] = f0.x; o[1] = f0.y; o[2] = f1.x; o[3] = f1.y;
    o[4] = f2.x; o[5] = f2.y; o[6] = f3.x; o[7] = f3.y;
}

// convert an already-loaded 16B of halves -> 8 floats
__device__ __forceinline__ void cvt_h8(float4 r, float* o) {
    __half2 h0 = *reinterpret_cast<__half2*>(&r.x);
    __half2 h1 = *reinterpret_cast<__half2*>(&r.y);
    __half2 h2 = *reinterpret_cast<__half2*>(&r.z);
    __half2 h3 = *reinterpret_cast<__half2*>(&r.w);
    float2 f0 = __half22float2(h0), f1 = __half22float2(h1);
    float2 f2 = __half22float2(h2), f3 = __half22float2(h3);
    o[0] = f0.x; o[1] = f0.y; o[2] = f1.x; o[3] = f1.y;
    o[4] = f2.x; o[5] = f2.y; o[6] = f3.x; o[7] = f3.y;
}

// ---------------- emulsion edge pass + fold --------------------------------
// 8 nodes/wave, 8 lanes/node, 8 features/lane. Software-pipelined: next
// pair's index + 128B u-row prefetched (raw float4) while current pair is
// consumed -> gather latency hidden behind VALU; VGPR stays <=64.
// x[n] = (x[n] + sum_e relu(u[dst]+v[n]+ef*we)) / 2   (node-local update)
__device__ __forceinline__ void em_consume(
        unsigned e, float4 r, const float* vn, const float* wef, float* acc) {
    float uj[8];
    cvt_h8(r, uj);
    float ef = __half2float(__ushort_as_half((unsigned short)(e & 0xffff)));
    #pragma unroll
    for (int j = 0; j < 8; ++j)
        acc[j] += fmaxf(uj[j] + vn[j] + ef * wef[j], 0.f);
}

__global__ __launch_bounds__(256) void em_edge(
        const unsigned* __restrict__ em_val, const int* __restrict__ ofs,
        const __half* __restrict__ u, const __half* __restrict__ v,
        const float* __restrict__ we, float* __restrict__ x, int order) {
    int t = threadIdx.x;
    int node = blockIdx.x * 32 + (t >> 3);
    if (node >= NN) return;
    int f0 = (t & 7) * 8;
    int key = order * NN + node;
    int s0 = ofs[key], s1 = ofs[key + 1];
    float vn[8], wef[8], acc[8] = {};
    load_h8(&v[(size_t)node * HD + f0], vn);
    *(float4*)&wef[0] = *(const float4*)&we[f0];
    *(float4*)&wef[4] = *(const float4*)&we[f0 + 4];
    int p = s0, n = s1 - s0;
    unsigned ea = 0, eb = 0;
    float4 ra, rb;
    if (n >= 2) {
        ea = em_val[p]; eb = em_val[p + 1];
        ra = *(const float4*)&u[(size_t)(ea >> 16) * HD + f0];
        rb = *(const float4*)&u[(size_t)(eb >> 16) * HD + f0];
    }
    for (; p + 4 <= s1; p += 2) {
        unsigned na = em_val[p + 2], nb = em_val[p + 3];
        float4 qa = *(const float4*)&u[(size_t)(na >> 16) * HD + f0];
        float4 qb = *(const float4*)&u[(size_t)(nb >> 16) * HD + f0];
        em_consume(ea, ra, vn, wef, acc);
        em_consume(eb, rb, vn, wef, acc);
        ea = na; eb = nb; ra = qa; rb = qb;
    }
    if (n >= 2) {
        em_consume(ea, ra, vn, wef, acc);
        em_consume(eb, rb, vn, wef, acc);
        p += 2;
    }
    if (p < s1) {
        unsigned e0 = em_val[p];
        float4 r0 = *(const float4*)&u[(size_t)(e0 >> 16) * HD + f0];
        em_consume(e0, r0, vn, wef, acc);
    }
    float xr[8];
    *(float4*)&xr[0] = *(const float4*)&x[(size_t)node * HD + f0];
    *(float4*)&xr[4] = *(const float4*)&x[(size_t)node * HD + f0 + 4];
    #pragma unroll
    for (int j = 0; j < 8; ++j) xr[j] = (xr[j] + acc[j]) * 0.5f;
    *(float4*)&x[(size_t)node * HD + f0] = *(float4*)&xr[0];
    *(float4*)&x[(size_t)node * HD + f0 + 4] = *(float4*)&xr[4];
}

// ---------------- edge conv pass -------------------------------------------
// max_e relu(u[n]+v[src]) == relu(u[n] + max_e v[src])  (fp-exact). Pipelined
// like em_edge; empty segment -> 0.
__device__ __forceinline__ void ec_consume(float4 r, float* m) {
    float vj[8];
    cvt_h8(r, vj);
    #pragma unroll
    for (int j = 0; j < 8; ++j) m[j] = fmaxf(m[j], vj[j]);
}

__global__ __launch_bounds__(256) void ec_edge(
        const int* __restrict__ ec_val, const int* __restrict__ ofs,
        const __half* __restrict__ u, const __half* __restrict__ v,
        float* __restrict__ x) {
    int t = threadIdx.x;
    int node = blockIdx.x * 32 + (t >> 3);
    if (node >= NN) return;
    int f0 = (t & 7) * 8;
    int s0 = ofs[4 * NN + node] - NE, s1 = ofs[4 * NN + node + 1] - NE;
    float o[8];
    int n = s1 - s0;
    if (n > 0) {
        float m[8];
        #pragma unroll
        for (int j = 0; j < 8; ++j) m[j] = -3.0e38f;
        int p = s0;
        float4 ra, rb;
        if (n >= 2) {
            int ia = ec_val[p], ib = ec_val[p + 1];
            ra = *(const float4*)&v[(size_t)ia * HD + f0];
            rb = *(const float4*)&v[(size_t)ib * HD + f0];
        }
        for (; p + 4 <= s1; p += 2) {
            int na = ec_val[p + 2], nb = ec_val[p + 3];
            float4 qa = *(const float4*)&v[(size_t)na * HD + f0];
            float4 qb = *(const float4*)&v[(size_t)nb * HD + f0];
            ec_consume(ra, m);
            ec_consume(rb, m);
            ra = qa; rb = qb;
        }
        if (n >= 2) {
            ec_consume(ra, m);
            ec_consume(rb, m);
            p += 2;
        }
        if (p < s1) {
            int i0 = ec_val[p];
            float4 r0 = *(const float4*)&v[(size_t)i0 * HD + f0];
            ec_consume(r0, m);
        }
        float un[8];
        load_h8(&u[(size_t)node * HD + f0], un);
        #pragma unroll
        for (int j = 0; j < 8; ++j) o[j] = fmaxf(un[j] + m[j], 0.f);
    } else {
        #pragma unroll
        for (int j = 0; j < 8; ++j) o[j] = 0.f;
    }
    *(float4*)&x[(size_t)node * HD + f0] = *(float4*)&o[0];
    *(float4*)&x[(size_t)node * HD + f0 + 4] = *(float4*)&o[4];
}

// ---------------- linear: x = relu(x @ W + b), scalar fp32 ------------------
template<int K>
__global__ __launch_bounds__(256) void lin_kernel(
        const float* __restrict__ xin,
        const float* __restrict__ W, const float* __restrict__ bias,
        float* __restrict__ xout) {
    __shared__ float xs[64][K + 1];
    int t = threadIdx.x;
    int n0 = blockIdx.x * 64;
    for (int idx = t; idx < 64 * K; idx += 256) {
        int n = idx / K, k = idx - n * K;
        int g = n0 + n;
        xs[n][k] = (g < NN) ? xin[(size_t)g * K + k] : 0.f;
    }
    __syncthreads();
    int ng = t >> 4;
    int f0 = (t & 15) * 4;
    float acc[4][4] = {};
    for (int k = 0; k < K; ++k) {
        float4 w4 = *(const float4*)&W[k * HD + f0];
        #pragma unroll
        for (int j = 0; j < 4; ++j) {
            float xv = xs[ng * 4 + j][k];
            acc[j][0] += xv * w4.x; acc[j][1] += xv * w4.y;
            acc[j][2] += xv * w4.z; acc[j][3] += xv * w4.w;
        }
    }
    float4 b4 = *(const float4*)&bias[f0];
    #pragma unroll
    for (int j = 0; j < 4; ++j) {
        int g = n0 + ng * 4 + j;
        if (g < NN) {
            float4 o;
            o.x = fmaxf(acc[j][0] + b4.x, 0.f);
            o.y = fmaxf(acc[j][1] + b4.y, 0.f);
            o.z = fmaxf(acc[j][2] + b4.z, 0.f);
            o.w = fmaxf(acc[j][3] + b4.w, 0.f);
            *(float4*)&xout[(size_t)g * HD + f0] = o;
        }
    }
}

// ---------------- output projection ----------------------------------------
__global__ __launch_bounds__(256) void out_kernel(
        const float* __restrict__ x, const float* __restrict__ W,
        const float* __restrict__ bias, float* __restrict__ out) {
    int n = blockIdx.x * 256 + threadIdx.x;
    if (n >= NN) return;
    float xr[HD];
    #pragma unroll
    for (int k = 0; k < HD; k += 4) {
        float4 t4 = *(const float4*)&x[(size_t)n * HD + k];
        xr[k] = t4.x; xr[k + 1] = t4.y; xr[k + 2] = t4.z; xr[k + 3] = t4.w;
    }
    #pragma unroll
    for (int f = 0; f < 10; ++f) {
        float acc = bias[f];
        #pragma unroll
        for (int k = 0; k < HD; ++k) acc += xr[k] * W[k * 10 + f];
        out[(size_t)n * 10 + f] = acc;
    }
}

extern "C" void kernel_launch(void* const* d_in, const int* in_sizes, int n_in,
                              void* d_out, int out_size, void* d_ws, size_t ws_size,
                              hipStream_t stream) {
    const float* x_in  = (const float*)d_in[0];
    const int*   ei    = (const int*)d_in[1];
    const float* ef    = (const float*)d_in[2];
    const float* lw[3] = {(const float*)d_in[3], (const float*)d_in[5], (const float*)d_in[7]};
    const float* lb[3] = {(const float*)d_in[4], (const float*)d_in[6], (const float*)d_in[8]};
    const float* em_w  = (const float*)d_in[9];
    const float* em_b  = (const float*)d_in[10];
    const float* ec_w  = (const float*)d_in[11];
    const float* ec_b  = (const float*)d_in[12];
    const float* ow    = (const float*)d_in[13];
    const float* ob    = (const float*)d_in[14];
    float* out = (float*)d_out;

    char* wsb = (char*)d_ws;
    size_t off = 0;
    auto alloc = [&](size_t bytes) {
        void* p = wsb + off;
        off = (off + bytes + 255) & ~(size_t)255;
        return p;
    };
    float*     x      = (float*)alloc((size_t)NN * HD * 4);
    _Float16*  u      = (_Float16*)alloc((size_t)NN * HD * 2);
    _Float16*  v      = (_Float16*)alloc((size_t)NN * HD * 2);
    int*       cnt    = (int*)alloc((size_t)NKEY * 4);
    int*       ofs    = (int*)alloc((size_t)NKEY * 4);
    int*       bsum   = (int*)alloc((size_t)1024 * 4);
    uchar2*    rank   = (uchar2*)alloc((size_t)NE * 2);
    unsigned*  em_val = (unsigned*)alloc((size_t)NE * 4);
    int*       ec_val = (int*)alloc((size_t)NE * 4);
    _Float16*  wh     = (_Float16*)alloc((size_t)24 * 4096 * 2);
    (void)ws_size; (void)in_sizes; (void)n_in; (void)out_size;

    const int gb_n8 = (NN + 31) / 32;   // 1563

    // ---- CSR build + weight prep + lin0 (fused front) ----
    hipMemsetAsync(cnt, 0, (size_t)NKEY * 4, stream);
    k_front<<<GB_CNT + GB_PREP + GB_LIN, 256, 0, stream>>>(
        ei, cnt, rank, em_w, ec_w, wh, x_in, lw[0], lb[0], x);
    scan_blk<<<GB_KEYS, 256, 0, stream>>>(cnt, bsum);
    scan_fin2<<<GB_KEYS, 256, 0, stream>>>(cnt, bsum, ofs);

    // fill fused with layer-0/order-0 uv GEMM
    k_fill_uv<<<GB_CNT + GB_LIN, 256, 0, stream>>>(
        ei, ef, ofs, rank, em_val, ec_val, x,
        wh, wh + (size_t)12 * 4096, wh + (size_t)3 * 4096, wh + (size_t)15 * 4096,
        em_b, u, v);

    // ---- network ----
    for (int i = 0; i < 3; ++i) {
        const _Float16* Wuh = wh + (size_t)i * 4096;
        const _Float16* Wvh = wh + (size_t)(3 + i) * 4096;
        const _Float16* Wul = wh + (size_t)(12 + i) * 4096;
        const _Float16* Wvl = wh + (size_t)(15 + i) * 4096;
        const float* bi = em_b + (size_t)i * HD;
        const float* we = em_w + (size_t)i * 129 * HD + 128 * HD;
        for (int o = 0; o < 4; ++o) {
            if (!(i == 0 && o == 0))
                uv_slim<<<GB_LIN, 256, 0, stream>>>(x, Wuh, Wul, Wvh, Wvl, bi, u, v);
            em_edge<<<gb_n8, 256, 0, stream>>>(em_val, ofs, (const __half*)u,
                                               (const __half*)v, we, x, o);
        }
        if (i < 2)
            lin_kernel<64><<<GB_LIN, 256, 0, stream>>>(x, lw[i + 1], lb[i + 1], x);
    }

    for (int j = 0; j < 3; ++j) {
        const _Float16* Wuh = wh + (size_t)(6 + j) * 4096;
        const _Float16* Wvh = wh + (size_t)(9 + j) * 4096;
        const _Float16* Wul = wh + (size_t)(18 + j) * 4096;
        const _Float16* Wvl = wh + (size_t)(21 + j) * 4096;
        const float* bj = ec_b + (size_t)j * HD;
        uv_slim<<<GB_LIN, 256, 0, stream>>>(x, Wuh, Wul, Wvh, Wvl, bj, u, v);
        ec_edge<<<gb_n8, 256, 0, stream>>>(ec_val, ofs, (const __half*)u,
                                           (const __half*)v, x);
    }

    out_kernel<<<(NN + 255) / 256, 256, 0, stream>>>(x, ow, ob, out);
}